// Round 13
// baseline (90.290 us; speedup 1.0000x reference)
//
#include <hip/hip_runtime.h>
#include <hip/hip_bf16.h>

// ContrastiveLoss (SupCon-style), N=4096 rows, K=256 dim, TEMP=0.5.
// loss = mean over same-label off-diag pairs of [log(neg_i + e_ij) - t2_ij].
// e <= e^2 ~ 7.4, neg >= ~550 -> log(neg+e) = log n + e/n (2nd-order dropped,
// <=1e-4 rel [R7]). Stats symmetric (e_ij = e_ji) -> per-COLUMN sums:
// exsum, pexp, pt2, pcnt; neg = exsum - pexp;
// loss = S_j [c log n + pe/n - tt] / S_j c.
//
// R13: tile-pair pipelining. 512 blocks x (2 j-tiles each): A-frags loaded
// once per block (VGPR, reused both tiles; wave-loads 96->80 per tile-pair,
// R9's measured transaction slope ~8us/100% -> ~1.3us), and tile-1's B-panel
// gll16s are issued right after tile-0's compute barrier so tile-0's long
// VALU-only epilogue (~2000cyc: 64 quarter-rate exps + ~700 VALU per lane)
// runs WHILE tile-1's staging drains — the drain-overlap m97's 2-barrier
// loop can't express, available here because the epilogue needs no LDS.
// [R12: 78.9us; fill 41us is harness-fixed at HBM roofline]
//
// pk8 layout per 16-row tile (4096 B):
//   byte[u*1024 + quad*256 + r16*16 + h*8 + j] = fp8(norm8[r16][quad*8+(2u+h)*32+j])
// -> chunk (tile,u) = 1KB = one gll16/dwordx4 row; lane's 16B = c-steps
// {2u,2u+1} (k_local = quad*8 + j).
// C/D: col = lane&15, row = (lane>>4)*4 + reg  [learn_hip m89/m91; R3-R12
// validated end-to-end]. x8 scaling; acc = 64*sim -> t2 = acc * 2^-5 exact.
//
// ws: [0,1MB) pk8; [2MB,6MB) part[4][64][4096] f32; [6MB,+16B) acc[4]
//   (acc[0]=loss, acc[1]=cnt, acc[2]=ticket, acc[3]=pad).

#define N_ROWS 4096
#define K_DIM  256

typedef __attribute__((ext_vector_type(4))) float float4v;    // MFMA C/D
typedef __attribute__((ext_vector_type(4))) float f4;
typedef __attribute__((ext_vector_type(4))) int   int4v;
typedef __attribute__((ext_vector_type(2))) long  long2v;     // 2 x 8B frags

#define PK_OFF    0
#define PART_OFF  (2 * 1024 * 1024)
#define ACC_OFF   (PART_OFF + 4 * 64 * N_ROWS * 4)     // +4 MB

// async global->LDS, 16B/lane: dest = wave-uniform base + lane*16 [m97 path]
__device__ __forceinline__ void gll16(const void* g, void* l) {
    __builtin_amdgcn_global_load_lds(
        (const __attribute__((address_space(1))) unsigned int*)g,
        (__attribute__((address_space(3))) unsigned int*)l, 16, 0, 0);
}

// ---------------------------------------------------------------------------
// K1: block = one 16-row tile. Coalesced float4 loads -> LDS, per-row norms
// via 16-lane shuffle groups, x8-scaled fp8 pack, 16B/thread coalesced store.
__global__ void normalize_kernel(const float* __restrict__ emb,
                                 unsigned char* __restrict__ pk8,
                                 float* __restrict__ acc) {
    int tile = blockIdx.x, t = threadIdx.x;
    __shared__ float lds[16 * 256];
    __shared__ float sc[16];
    const f4* src = (const f4*)(emb + tile * 16 * 256);
    f4* dst4 = (f4*)lds;
    #pragma unroll
    for (int it = 0; it < 4; ++it) dst4[t + 256 * it] = src[t + 256 * it];
    __syncthreads();
    int wave = t >> 6, lane = t & 63;
    int row = wave * 4 + (lane >> 4);          // 4 rows per wave
    float s = 0.f;
    #pragma unroll
    for (int m = 0; m < 16; ++m) {
        float x = lds[row * 256 + (lane & 15) + 16 * m];
        s += x * x;
    }
    s += __shfl_xor(s, 1); s += __shfl_xor(s, 2);
    s += __shfl_xor(s, 4); s += __shfl_xor(s, 8);
    float scale = 1.0f / fmaxf(sqrtf(s), 1e-12f);
    if ((lane & 15) == 0) sc[row] = scale;
    __syncthreads();
    int u = t >> 6, quad = (t >> 4) & 3, r16 = t & 15;
    float s8 = sc[r16] * 8.0f;
    const float* lr = lds + r16 * 256;
    int4v wv;
    #pragma unroll
    for (int wi = 0; wi < 4; ++wi) {           // word wi = bytes 4wi..4wi+3
        int h  = wi >> 1;
        int j0 = (wi & 1) * 4;
        int kb = quad * 8 + (2 * u + h) * 32 + j0;
        float v0 = lr[kb + 0] * s8, v1 = lr[kb + 1] * s8;
        float v2 = lr[kb + 2] * s8, v3 = lr[kb + 3] * s8;
        int wd = __builtin_amdgcn_cvt_pk_fp8_f32(v0, v1, 0, 0);
        wd     = __builtin_amdgcn_cvt_pk_fp8_f32(v2, v3, wd, 1);
        wv[wi] = wd;
    }
    *(int4v*)(pk8 + tile * 4096 + t * 16) = wv;
    if (tile == 0 && t < 4) acc[t] = 0.0f;     // loss, cnt, ticket, pad
}

// ---------------------------------------------------------------------------
// K2: fp8 fused sim/exp/stats, tile-pair pipelined. Grid 512: block (bi,bjg)
// = 128 rows x 2 j-tiles (bj = bjg*2, bjg*2+1). A-frags in VGPRs (loaded
// once). Per tile: 32 B-gll16 staged; tile1's staging overlaps tile0's
// epilogue. 32KB LDS, launch_bounds(256,3).
__global__ __launch_bounds__(256, 3)
void negsum_kernel(const unsigned char* __restrict__ pk8,
                   const int* __restrict__ labels,
                   float* __restrict__ part) {
    __shared__ __align__(16) unsigned char Bs8[32768];   // 8 tiles x 4 chunks
    int t = threadIdx.x;
    int w = t >> 6, lane = t & 63;
    int lane16 = lane & 15, quad = lane >> 4;
    int bi  = blockIdx.x >> 4;                 // 0..31
    int bjg = blockIdx.x & 15;                 // 0..15 -> bj = bjg*2 + tile
    int wi = w >> 1, wj = w & 1;
    int ibase = bi * 128 + wi * 64;
    const char* pkb = (const char*)pk8;        // tile16 = 4KB, chunk = 1KB

    // ---- stage B-panel for tile 0 (async, 8 gll16 per wave) ----
    {
        int bj0 = bjg * 2;
        #pragma unroll
        for (int u = 0; u < 8; ++u) {
            int c8 = w * 8 + u, tl = c8 >> 2, cs = c8 & 3;
            gll16(pkb + (((bj0 * 8 + tl) << 12) | (cs << 10)) + lane * 16,
                  Bs8 + (c8 << 10));
        }
    }
    // ---- A-frags once per block (4 it-tiles x 4 cs, 16B each) ----
    long2v av[4][4];
    #pragma unroll
    for (int it = 0; it < 4; ++it)
        #pragma unroll
        for (int cs = 0; cs < 4; ++cs)
            av[it][cs] = *(const long2v*)(pkb
                + (((bi * 8 + wi * 4 + it) << 12) | (cs << 10)) + lane * 16);
    int labi[16];
    #pragma unroll
    for (int it = 0; it < 4; ++it)
        #pragma unroll
        for (int r = 0; r < 4; ++r)
            labi[it * 4 + r] = labels[ibase + it * 16 + quad * 4 + r];
    int i64 = bi * 2 + wi;

    __syncthreads();                           // drain tile-0 staging + A

    #pragma unroll
    for (int tile = 0; tile < 2; ++tile) {
        int bj = bjg * 2 + tile;
        int jbase = bj * 128 + wj * 64;
        int labj[4];
        #pragma unroll
        for (int jt = 0; jt < 4; ++jt)
            labj[jt] = labels[jbase + jt * 16 + lane16];

        float4v acc[4][4];
        #pragma unroll
        for (int a = 0; a < 4; ++a)
            #pragma unroll
            for (int b = 0; b < 4; ++b)
                acc[a][b] = (float4v){0.f, 0.f, 0.f, 0.f};

        #pragma unroll
        for (int cs = 0; cs < 4; ++cs) {
            long2v bv[4];
            #pragma unroll
            for (int jt = 0; jt < 4; ++jt)
                bv[jt] = *(const long2v*)(Bs8
                         + (((((wj * 4 + jt) << 2) | cs) << 10)) + lane * 16);
            #pragma unroll
            for (int h = 0; h < 2; ++h)
                #pragma unroll
                for (int it = 0; it < 4; ++it)
                    #pragma unroll
                    for (int jt = 0; jt < 4; ++jt)
                        acc[it][jt] = __builtin_amdgcn_mfma_f32_16x16x32_fp8_fp8(
                            av[it][cs][h], bv[jt][h], acc[it][jt], 0, 0, 0);
        }

        __syncthreads();                       // all ds_reads of Bs done
        if (tile == 0) {                       // stage tile-1 B-panel NOW;
            int bj1 = bjg * 2 + 1;             // drains during epilogue below
            #pragma unroll
            for (int u = 0; u < 8; ++u) {
                int c8 = w * 8 + u, tl = c8 >> 2, cs = c8 & 3;
                gll16(pkb + (((bj1 * 8 + tl) << 12) | (cs << 10)) + lane * 16,
                      Bs8 + (c8 << 10));
            }
        }

        // epilogue (VALU-only, no LDS): per-column stats; acc = 64*sim
        float ex[4] = {0,0,0,0}, pe[4] = {0,0,0,0};
        float tt[4] = {0,0,0,0}, pc[4] = {0,0,0,0};
        #pragma unroll
        for (int it = 0; it < 4; ++it) {
            #pragma unroll
            for (int jt = 0; jt < 4; ++jt) {
                int j = jbase + jt * 16 + lane16;
                #pragma unroll
                for (int r = 0; r < 4; ++r) {
                    int i = ibase + it * 16 + quad * 4 + r;
                    float t2 = acc[it][jt][r] * 0.03125f;   // 2*sim, exact
                    float e  = __expf(t2);
                    bool keep = (i != j);
                    bool same = (labi[it * 4 + r] == labj[jt]);
                    ex[jt] += keep ? e : 0.0f;
                    float m = (same && keep) ? 1.0f : 0.0f;
                    pe[jt] = fmaf(m, e,  pe[jt]);
                    tt[jt] = fmaf(m, t2, tt[jt]);
                    pc[jt] += m;
                }
            }
        }
        #pragma unroll
        for (int jt = 0; jt < 4; ++jt) {
            float v0 = ex[jt], v1 = pe[jt], v2 = tt[jt], v3 = pc[jt];
            v0 += __shfl_xor(v0, 16); v0 += __shfl_xor(v0, 32);
            v1 += __shfl_xor(v1, 16); v1 += __shfl_xor(v1, 32);
            v2 += __shfl_xor(v2, 16); v2 += __shfl_xor(v2, 32);
            v3 += __shfl_xor(v3, 16); v3 += __shfl_xor(v3, 32);
            if (quad == 0) {
                int col = jbase + jt * 16 + lane16;
                part[((0 * 64 + i64) << 12) + col] = v0;
                part[((1 * 64 + i64) << 12) + col] = v1;
                part[((2 * 64 + i64) << 12) + col] = v2;
                part[((3 * 64 + i64) << 12) + col] = v3;
            }
        }
        if (tile == 0) __syncthreads();        // drain tile-1 staging
    }
}

// ---------------------------------------------------------------------------
// K3: slice-parallel rowreduce. Grid 128 x 256: block = 32 rows; thread
// (rl = t>>3, sl = t&7) sums 8 chunks of row; shfl over slices, closed form,
// wave+block reduce, ticket finalize.
__global__ void rowreduce_kernel(const float* __restrict__ part,
                                 float* __restrict__ acc,
                                 float* __restrict__ out) {
    int t = threadIdx.x;
    int rl = t >> 3, sl = t & 7;
    int row = blockIdx.x * 32 + rl;
    float s[4];
    #pragma unroll
    for (int st = 0; st < 4; ++st) {
        float v = 0.f;
        #pragma unroll
        for (int c = 0; c < 8; ++c)
            v += part[((st * 64 + (sl * 8 + c)) << 12) + row];
        s[st] = v;
    }
    #pragma unroll
    for (int st = 0; st < 4; ++st) {
        s[st] += __shfl_xor(s[st], 1);
        s[st] += __shfl_xor(s[st], 2);
        s[st] += __shfl_xor(s[st], 4);
    }
    float lsum = 0.f, pcm = 0.f;
    if (sl == 0 && s[3] > 0.f) {
        float n = s[0] - s[1];                 // neg = exsum - pexp
        lsum = s[3] * logf(n) + s[1] / n - s[2];
        pcm  = s[3];
    }
    #pragma unroll
    for (int m = 1; m < 64; m <<= 1) {
        lsum += __shfl_xor(lsum, m);
        pcm  += __shfl_xor(pcm,  m);
    }
    __shared__ float sl4[4], sc4[4];
    int wave = t >> 6, lane = t & 63;
    if (lane == 0) { sl4[wave] = lsum; sc4[wave] = pcm; }
    __syncthreads();
    if (t == 0) {
        atomicAdd(&acc[0], sl4[0] + sl4[1] + sl4[2] + sl4[3]);
        atomicAdd(&acc[1], sc4[0] + sc4[1] + sc4[2] + sc4[3]);
        __threadfence();
        int ticket = atomicAdd((int*)(acc + 2), 1);
        if (ticket == 127) {
            float ls = atomicAdd(&acc[0], 0.0f);
            float cs = atomicAdd(&acc[1], 0.0f);
            out[0] = ls / cs;
        }
    }
}

// ---------------------------------------------------------------------------
extern "C" void kernel_launch(void* const* d_in, const int* in_sizes, int n_in,
                              void* d_out, int out_size, void* d_ws, size_t ws_size,
                              hipStream_t stream) {
    const float* emb    = (const float*)d_in[0];
    const int*   labels = (const int*)d_in[1];
    float* out = (float*)d_out;
    char*  ws  = (char*)d_ws;

    unsigned char* pk8  = (unsigned char*)(ws + PK_OFF);
    float*         part = (float*)(ws + PART_OFF);
    float*         acc  = (float*)(ws + ACC_OFF);

    normalize_kernel<<<N_ROWS / 16, 256, 0, stream>>>(emb, pk8, acc);
    negsum_kernel<<<512, 256, 0, stream>>>(pk8, labels, part);
    rowreduce_kernel<<<128, 256, 0, stream>>>(part, acc, out);
}

// Round 14
// 78.938 us; speedup vs baseline: 1.1438x; 1.1438x over previous
//
#include <hip/hip_runtime.h>
#include <hip/hip_bf16.h>

// ContrastiveLoss (SupCon-style), N=4096 rows, K=256 dim, TEMP=0.5.
// loss = mean over same-label off-diag pairs of [log(neg_i + e_ij) - t2_ij].
// e <= e^2 ~ 7.4, neg >= ~550 -> log(neg+e) = log n + e/n (2nd-order dropped,
// <=1e-4 rel [R7]). Stats symmetric (e_ij = e_ji) -> per-COLUMN sums:
// exsum, pexp, pt2, pcnt; neg = exsum - pexp;
// loss = S_j [c log n + pe/n - tt] / S_j c.
//
// R14 = exact revert to R12 (best: 78.9us). R13's tile-pair pipelining
// REGRESSED (+11us): mid-loop gll16s share vmcnt with epilogue stores ->
// compiler serializes; grid halved hurt round-robin. Consistent with
// m131-m141: source-level pipelining tweaks on this structure are
// neutral-to-negative. R12 budget: fill ~41 (harness-fixed, at HBM
// roofline), normalize ~4, negsum ~28, rowreduce ~2, gaps ~4.
//
// pk8 layout per 16-row tile (4096 B):
//   byte[u*1024 + quad*256 + r16*16 + h*8 + j] = fp8(norm8[r16][quad*8+(2u+h)*32+j])
// -> chunk (tile,u) = 1KB = one gll16/dwordx4 row; lane's 16B = c-steps
// {2u,2u+1} (k_local = quad*8 + j).
// C/D: col = lane&15, row = (lane>>4)*4 + reg  [learn_hip m89/m91; R3-R13
// validated end-to-end]. x8 scaling; acc = 64*sim -> t2 = acc * 2^-5 exact.
//
// ws: [0,1MB) pk8; [2MB,6MB) part[4][64][4096] f32; [6MB,+16B) acc[4]
//   (acc[0]=loss, acc[1]=cnt, acc[2]=ticket, acc[3]=pad).

#define N_ROWS 4096
#define K_DIM  256

typedef __attribute__((ext_vector_type(4))) float float4v;    // MFMA C/D
typedef __attribute__((ext_vector_type(4))) float f4;
typedef __attribute__((ext_vector_type(4))) int   int4v;
typedef __attribute__((ext_vector_type(2))) long  long2v;     // 2 x 8B frags

#define PK_OFF    0
#define PART_OFF  (2 * 1024 * 1024)
#define ACC_OFF   (PART_OFF + 4 * 64 * N_ROWS * 4)     // +4 MB

// async global->LDS, 16B/lane: dest = wave-uniform base + lane*16 [m97 path]
__device__ __forceinline__ void gll16(const void* g, void* l) {
    __builtin_amdgcn_global_load_lds(
        (const __attribute__((address_space(1))) unsigned int*)g,
        (__attribute__((address_space(3))) unsigned int*)l, 16, 0, 0);
}

// ---------------------------------------------------------------------------
// K1: block = one 16-row tile. Coalesced float4 loads -> LDS, per-row norms
// via 16-lane shuffle groups, x8-scaled fp8 pack, 16B/thread coalesced store.
__global__ void normalize_kernel(const float* __restrict__ emb,
                                 unsigned char* __restrict__ pk8,
                                 float* __restrict__ acc) {
    int tile = blockIdx.x, t = threadIdx.x;
    __shared__ float lds[16 * 256];
    __shared__ float sc[16];
    const f4* src = (const f4*)(emb + tile * 16 * 256);
    f4* dst4 = (f4*)lds;
    #pragma unroll
    for (int it = 0; it < 4; ++it) dst4[t + 256 * it] = src[t + 256 * it];
    __syncthreads();
    int wave = t >> 6, lane = t & 63;
    int row = wave * 4 + (lane >> 4);          // 4 rows per wave
    float s = 0.f;
    #pragma unroll
    for (int m = 0; m < 16; ++m) {
        float x = lds[row * 256 + (lane & 15) + 16 * m];
        s += x * x;
    }
    s += __shfl_xor(s, 1); s += __shfl_xor(s, 2);
    s += __shfl_xor(s, 4); s += __shfl_xor(s, 8);
    float scale = 1.0f / fmaxf(sqrtf(s), 1e-12f);
    if ((lane & 15) == 0) sc[row] = scale;
    __syncthreads();
    // pack 16 bytes: fixed (u, quad, r16) per thread; h,j sweep the 16B
    int u = t >> 6, quad = (t >> 4) & 3, r16 = t & 15;
    float s8 = sc[r16] * 8.0f;
    const float* lr = lds + r16 * 256;
    int4v wv;
    #pragma unroll
    for (int wi = 0; wi < 4; ++wi) {           // word wi = bytes 4wi..4wi+3
        int h  = wi >> 1;
        int j0 = (wi & 1) * 4;
        int kb = quad * 8 + (2 * u + h) * 32 + j0;
        float v0 = lr[kb + 0] * s8, v1 = lr[kb + 1] * s8;
        float v2 = lr[kb + 2] * s8, v3 = lr[kb + 3] * s8;
        int wd = __builtin_amdgcn_cvt_pk_fp8_f32(v0, v1, 0, 0);
        wd     = __builtin_amdgcn_cvt_pk_fp8_f32(v2, v3, wd, 1);
        wv[wi] = wd;
    }
    *(int4v*)(pk8 + tile * 4096 + t * 16) = wv;
    if (tile == 0 && t < 4) acc[t] = 0.0f;     // loss, cnt, ticket, pad
}

// ---------------------------------------------------------------------------
// K2: fp8 fused sim/exp/stats. Grid 1024 (XCD-swizzled) = 32x32 blocktiles of
// 128x128; 4 waves in 2x2, each a 64x64 subtile (4x4 MFMA frags).
// B-panel (32KB) staged via gll16 (async); A-frags loaded straight to VGPRs
// (16 dwordx4/wave, in flight alongside the gll16s). ONE barrier, then
// 16 ds_read_b128 + 128 MFMA per wave. 32KB LDS -> 3 blocks/CU.
__global__ __launch_bounds__(256, 3)
void negsum_kernel(const unsigned char* __restrict__ pk8,
                   const int* __restrict__ labels,
                   float* __restrict__ part) {
    __shared__ __align__(16) unsigned char Bs8[32768];   // 8 tiles x 4 chunks
    int t = threadIdx.x;
    int w = t >> 6, lane = t & 63;
    int lane16 = lane & 15, quad = lane >> 4;
    // XCD swizzle: 4 consecutive bi per XCD (A-panel stays L2-local)
    int xcd = blockIdx.x & 7, local = blockIdx.x >> 3;   // local 0..127
    int bi = xcd * 4 + (local >> 5);                     // 0..31
    int bj = local & 31;
    int wi = w >> 1, wj = w & 1;

    int ibase = bi * 128 + wi * 64;
    int jbase = bj * 128 + wj * 64;
    const char* pkb = (const char*)pk8;        // tile16 = 4KB, chunk = 1KB

    // ---- B-panel: 32 chunks of 1KB via async gll16 (8 per wave) ----
    #pragma unroll
    for (int u = 0; u < 8; ++u) {
        int c8 = w * 8 + u, tl = c8 >> 2, cs = c8 & 3;
        gll16(pkb + (((bj * 8 + tl) << 12) | (cs << 10)) + lane * 16,
              Bs8 + (c8 << 10));
    }
    // ---- A-frags straight to VGPRs (4 it-tiles x 4 cs, 16B each) ----
    long2v av[4][4];
    #pragma unroll
    for (int it = 0; it < 4; ++it)
        #pragma unroll
        for (int cs = 0; cs < 4; ++cs)
            av[it][cs] = *(const long2v*)(pkb
                + (((bi * 8 + wi * 4 + it) << 12) | (cs << 10)) + lane * 16);

    int labi[16], labj[4];
    #pragma unroll
    for (int it = 0; it < 4; ++it)
        #pragma unroll
        for (int r = 0; r < 4; ++r)
            labi[it * 4 + r] = labels[ibase + it * 16 + quad * 4 + r];
    #pragma unroll
    for (int jt = 0; jt < 4; ++jt)
        labj[jt] = labels[jbase + jt * 16 + lane16];

    float4v acc[4][4];
    #pragma unroll
    for (int a = 0; a < 4; ++a)
        #pragma unroll
        for (int b = 0; b < 4; ++b)
            acc[a][b] = (float4v){0.f, 0.f, 0.f, 0.f};

    __syncthreads();                           // drains gll16s (and A loads)

    #pragma unroll
    for (int cs = 0; cs < 4; ++cs) {
        long2v bv[4];
        #pragma unroll
        for (int jt = 0; jt < 4; ++jt)
            bv[jt] = *(const long2v*)(Bs8
                     + (((((wj * 4 + jt) << 2) | cs) << 10)) + lane * 16);
        #pragma unroll
        for (int h = 0; h < 2; ++h)
            #pragma unroll
            for (int it = 0; it < 4; ++it)
                #pragma unroll
                for (int jt = 0; jt < 4; ++jt)
                    acc[it][jt] = __builtin_amdgcn_mfma_f32_16x16x32_fp8_fp8(
                        av[it][cs][h], bv[jt][h], acc[it][jt], 0, 0, 0);
    }

    // epilogue: per-column stats (== per-row by symmetry); acc = 64*sim
    float ex[4] = {0,0,0,0}, pe[4] = {0,0,0,0};
    float tt[4] = {0,0,0,0}, pc[4] = {0,0,0,0};
    #pragma unroll
    for (int it = 0; it < 4; ++it) {
        #pragma unroll
        for (int jt = 0; jt < 4; ++jt) {
            int j = jbase + jt * 16 + lane16;
            #pragma unroll
            for (int r = 0; r < 4; ++r) {
                int i = ibase + it * 16 + quad * 4 + r;
                float t2 = acc[it][jt][r] * 0.03125f;   // 2*sim, exact pow2
                float e  = __expf(t2);
                bool keep = (i != j);
                bool same = (labi[it * 4 + r] == labj[jt]);
                ex[jt] += keep ? e : 0.0f;
                float m = (same && keep) ? 1.0f : 0.0f;
                pe[jt] = fmaf(m, e,  pe[jt]);
                tt[jt] = fmaf(m, t2, tt[jt]);
                pc[jt] += m;
            }
        }
    }
    int i64 = bi * 2 + wi;                     // this wave's 64-row chunk
    #pragma unroll
    for (int jt = 0; jt < 4; ++jt) {
        float v0 = ex[jt], v1 = pe[jt], v2 = tt[jt], v3 = pc[jt];
        v0 += __shfl_xor(v0, 16); v0 += __shfl_xor(v0, 32);
        v1 += __shfl_xor(v1, 16); v1 += __shfl_xor(v1, 32);
        v2 += __shfl_xor(v2, 16); v2 += __shfl_xor(v2, 32);
        v3 += __shfl_xor(v3, 16); v3 += __shfl_xor(v3, 32);
        if (quad == 0) {
            int col = jbase + jt * 16 + lane16;
            part[((0 * 64 + i64) << 12) + col] = v0;
            part[((1 * 64 + i64) << 12) + col] = v1;
            part[((2 * 64 + i64) << 12) + col] = v2;
            part[((3 * 64 + i64) << 12) + col] = v3;
        }
    }
}

// ---------------------------------------------------------------------------
// K3: slice-parallel rowreduce. Grid 128 x 256: block = 32 rows; thread
// (rl = t>>3, sl = t&7) sums 8 chunks of row (blk*32+rl); shfl over sl,
// per-row closed form on sl==0 lanes, wave+block reduce, ticket finalize.
__global__ void rowreduce_kernel(const float* __restrict__ part,
                                 float* __restrict__ acc,
                                 float* __restrict__ out) {
    int t = threadIdx.x;
    int rl = t >> 3, sl = t & 7;
    int row = blockIdx.x * 32 + rl;
    float s[4];
    #pragma unroll
    for (int st = 0; st < 4; ++st) {
        float v = 0.f;
        #pragma unroll
        for (int c = 0; c < 8; ++c)
            v += part[((st * 64 + (sl * 8 + c)) << 12) + row];
        s[st] = v;
    }
    #pragma unroll
    for (int st = 0; st < 4; ++st) {           // reduce over the 8 slices
        s[st] += __shfl_xor(s[st], 1);
        s[st] += __shfl_xor(s[st], 2);
        s[st] += __shfl_xor(s[st], 4);
    }
    float lsum = 0.f, pcm = 0.f;
    if (sl == 0 && s[3] > 0.f) {
        float n = s[0] - s[1];                 // neg = exsum - pexp
        lsum = s[3] * logf(n) + s[1] / n - s[2];
        pcm  = s[3];
    }
    #pragma unroll
    for (int m = 1; m < 64; m <<= 1) {         // full-wave sum (masked lanes=0)
        lsum += __shfl_xor(lsum, m);
        pcm  += __shfl_xor(pcm,  m);
    }
    __shared__ float sl4[4], sc4[4];
    int wave = t >> 6, lane = t & 63;
    if (lane == 0) { sl4[wave] = lsum; sc4[wave] = pcm; }
    __syncthreads();
    if (t == 0) {
        atomicAdd(&acc[0], sl4[0] + sl4[1] + sl4[2] + sl4[3]);
        atomicAdd(&acc[1], sc4[0] + sc4[1] + sc4[2] + sc4[3]);
        __threadfence();
        int ticket = atomicAdd((int*)(acc + 2), 1);
        if (ticket == 127) {
            float ls = atomicAdd(&acc[0], 0.0f);
            float cs = atomicAdd(&acc[1], 0.0f);
            out[0] = ls / cs;
        }
    }
}

// ---------------------------------------------------------------------------
extern "C" void kernel_launch(void* const* d_in, const int* in_sizes, int n_in,
                              void* d_out, int out_size, void* d_ws, size_t ws_size,
                              hipStream_t stream) {
    const float* emb    = (const float*)d_in[0];
    const int*   labels = (const int*)d_in[1];
    float* out = (float*)d_out;
    char*  ws  = (char*)d_ws;

    unsigned char* pk8  = (unsigned char*)(ws + PK_OFF);
    float*         part = (float*)(ws + PART_OFF);
    float*         acc  = (float*)(ws + ACC_OFF);

    normalize_kernel<<<N_ROWS / 16, 256, 0, stream>>>(emb, pk8, acc);
    negsum_kernel<<<1024, 256, 0, stream>>>(pk8, labels, part);
    rowreduce_kernel<<<128, 256, 0, stream>>>(part, acc, out);
}